// Round 2
// baseline (106.810 us; speedup 1.0000x reference)
//
#include <hip/hip_runtime.h>
#include <math.h>

// Problem: N=12000, F_IN=128, F_OUT=256, E=384000 (derived at runtime where easy)
#define F_IN 128
#define F_OUT 256

// ---------------------------------------------------------------------------
// Kernel A: set adjacency bits (symmetric). atomicOr is idempotent -> the
// resulting bitmap is deterministic regardless of edge order.
// bitmap row r (local to chunk) covers node r0+r; bit j = neighbor j.
// ---------------------------------------------------------------------------
__global__ void k_set_bits(const int* __restrict__ ei, int E,
                           unsigned* __restrict__ bm, int r0, int r1,
                           int row_words) {
    int e = blockIdx.x * blockDim.x + threadIdx.x;
    if (e >= E) return;
    int a = ei[e];
    int b = ei[E + e];
    if (a >= r0 && a < r1)
        atomicOr(&bm[(size_t)(a - r0) * row_words + (b >> 5)], 1u << (b & 31));
    if (b >= r0 && b < r1)
        atomicOr(&bm[(size_t)(b - r0) * row_words + (a >> 5)], 1u << (a & 31));
}

// ---------------------------------------------------------------------------
// Kernel B: popcount each bitmap row -> deg -> dinv = 1/sqrt(deg).
// One 64-lane wave per row; coalesced word reads; wave shuffle reduce.
// ---------------------------------------------------------------------------
__global__ void k_degree(const unsigned* __restrict__ bm,
                         float* __restrict__ dinv,
                         int r0, int rows, int row_words) {
    int row = blockIdx.x;
    if (row >= rows) return;
    const unsigned* p = bm + (size_t)row * row_words;
    int lane = threadIdx.x;           // blockDim.x == 64
    int cnt = 0;
    for (int w = lane; w < row_words; w += 64)
        cnt += __popc(p[w]);
    #pragma unroll
    for (int off = 32; off > 0; off >>= 1)
        cnt += __shfl_down(cnt, off, 64);
    if (lane == 0)
        dinv[r0 + row] = 1.0f / sqrtf((float)cnt);  // deg==0 -> inf, matches ref
}

// ---------------------------------------------------------------------------
// Kernel C: deterministic partial weighted column sums of x.
// 128 blocks x 128 threads; thread t owns column t within its block's row
// chunk. Coalesced x reads; dinv[r] is a wave-broadcast scalar load.
// partial[b*128 + t] = sum_{r in chunk_b} dinv[r] * x[r,t]
// ---------------------------------------------------------------------------
__global__ void k_weighted_colsum(const float* __restrict__ x,
                                  const float* __restrict__ dinv,
                                  float* __restrict__ partial, int n) {
    int t = threadIdx.x;                  // 0..127 (column)
    int b = blockIdx.x;                   // 0..127
    int rows_per = (n + gridDim.x - 1) / gridDim.x;
    int rbeg = b * rows_per;
    int rend = rbeg + rows_per; if (rend > n) rend = n;
    float acc = 0.f;
    for (int r = rbeg; r < rend; ++r)
        acc += dinv[r] * x[(size_t)r * F_IN + t];
    partial[(size_t)b * F_IN + t] = acc;
}

// ---------------------------------------------------------------------------
// Kernel D: single block. Reduce the 128 partials -> s[128] (in LDS), then
// agg[f] = sum_k s[k] * W[k,f].  W is (F_IN, F_OUT) row-major -> coalesced.
// ---------------------------------------------------------------------------
__global__ void k_reduce_and_agg(const float* __restrict__ partial, int nparts,
                                 const float* __restrict__ W,
                                 float* __restrict__ agg) {
    __shared__ float s[F_IN];
    int t = threadIdx.x;                  // 0..255
    if (t < F_IN) {
        float acc = 0.f;
        for (int b = 0; b < nparts; ++b)
            acc += partial[(size_t)b * F_IN + t];
        s[t] = acc;
    }
    __syncthreads();
    float a = 0.f;
    #pragma unroll 8
    for (int k = 0; k < F_IN; ++k)
        a += s[k] * W[(size_t)k * F_OUT + t];   // s[k]: LDS broadcast, no conflicts
    agg[t] = a;
}

// ---------------------------------------------------------------------------
// Kernel E: out[n,f] = dinv[n]*agg[f] + bias[f], float4-vectorized.
// ---------------------------------------------------------------------------
__global__ void k_outer(const float* __restrict__ dinv,
                        const float* __restrict__ agg,
                        const float* __restrict__ bias,
                        float4* __restrict__ out, int n) {
    int i = blockIdx.x * blockDim.x + threadIdx.x;
    const int per_row = F_OUT / 4;        // 64 float4 per node row
    int total = n * per_row;
    if (i >= total) return;
    int node = i / per_row;
    int f4   = i % per_row;
    float d = dinv[node];
    float4 a  = ((const float4*)agg)[f4];
    float4 bb = ((const float4*)bias)[f4];
    float4 o;
    o.x = d * a.x + bb.x;
    o.y = d * a.y + bb.y;
    o.z = d * a.z + bb.z;
    o.w = d * a.w + bb.w;
    out[i] = o;
}

// ---------------------------------------------------------------------------
static inline size_t align_up(size_t v, size_t a) { return (v + a - 1) & ~(a - 1); }

extern "C" void kernel_launch(void* const* d_in, const int* in_sizes, int n_in,
                              void* d_out, int out_size, void* d_ws, size_t ws_size,
                              hipStream_t stream) {
    const float* x    = (const float*)d_in[0];
    const int*   ei   = (const int*)  d_in[1];
    const float* W    = (const float*)d_in[2];
    const float* bias = (const float*)d_in[3];
    float* out = (float*)d_out;

    const int n = in_sizes[0] / F_IN;     // 12000
    const int E = in_sizes[1] / 2;        // 384000

    // bitmap geometry: ceil(n/32) words per row, padded to a multiple of 64
    // words so a 64-lane wave reads whole rows with no tail masking (padding
    // words are zeroed and never set since all node ids < n).
    const int row_words = (int)align_up((size_t)((n + 31) / 32), 64); // 384

    // workspace layout
    char* ws = (char*)d_ws;
    size_t off = 0;
    float* dinv = (float*)(ws + off);  off = align_up(off + (size_t)n * 4, 256);
    const int NPART = 128;
    float* partial = (float*)(ws + off); off = align_up(off + (size_t)NPART * F_IN * 4, 256);
    float* agg = (float*)(ws + off);   off = align_up(off + (size_t)F_OUT * 4, 256);
    unsigned* bm = (unsigned*)(ws + off);

    // how many bitmap rows fit in the remaining workspace (chunk if needed)
    size_t avail = (ws_size > off) ? (ws_size - off) : 0;
    long long fit = (long long)(avail / ((size_t)row_words * 4));
    int rows_per_chunk = (fit >= n) ? n : (fit > 0 ? (int)fit : 1);

    for (int r0 = 0; r0 < n; r0 += rows_per_chunk) {
        int rows = n - r0; if (rows > rows_per_chunk) rows = rows_per_chunk;
        (void)hipMemsetAsync(bm, 0, (size_t)rows * row_words * 4, stream);
        k_set_bits<<<(E + 255) / 256, 256, 0, stream>>>(ei, E, bm, r0, r0 + rows, row_words);
        k_degree<<<rows, 64, 0, stream>>>(bm, dinv, r0, rows, row_words);
    }

    k_weighted_colsum<<<NPART, F_IN, 0, stream>>>(x, dinv, partial, n);
    k_reduce_and_agg<<<1, F_OUT, 0, stream>>>(partial, NPART, W, agg);

    int total4 = n * (F_OUT / 4);
    k_outer<<<(total4 + 255) / 256, 256, 0, stream>>>((const float*)dinv, (const float*)agg,
                                                      (const float*)bias, (float4*)out, n);
}

// Round 3
// 103.532 us; speedup vs baseline: 1.0317x; 1.0317x over previous
//
#include <hip/hip_runtime.h>
#include <math.h>

#define F_IN 128
#define F_OUT 256

// ---------------------------------------------------------------------------
// Kernel A: set adjacency bits (symmetric) AND count distinct neighbors.
// atomicOr returns the old word -> exactly one thread per distinct bit sees
// it clear and increments deg. Integer atomics => deterministic.
// Chunked variant kept for tiny-workspace safety (normally one chunk).
// ---------------------------------------------------------------------------
__global__ void k_edges(const int* __restrict__ ei, int E,
                        unsigned* __restrict__ bm, int* __restrict__ deg,
                        int r0, int r1, int row_words) {
    int e = blockIdx.x * blockDim.x + threadIdx.x;
    if (e >= E) return;
    int a = ei[e];
    int b = ei[E + e];
    if (a >= r0 && a < r1) {
        unsigned mb = 1u << (b & 31);
        unsigned old = atomicOr(&bm[(size_t)(a - r0) * row_words + (b >> 5)], mb);
        if (!(old & mb)) atomicAdd(&deg[a], 1);
    }
    if (b >= r0 && b < r1) {
        unsigned ma = 1u << (a & 31);
        unsigned old = atomicOr(&bm[(size_t)(b - r0) * row_words + (a >> 5)], ma);
        if (!(old & ma)) atomicAdd(&deg[b], 1);
    }
}

// ---------------------------------------------------------------------------
// Kernel B: partial weighted column sums of x, float4-vectorized.
// 512 blocks x 256 threads. Thread (ro, c4) handles rows rbeg+ro, +8, ...
// for float4 column group c4. In-block LDS reduce over ro -> partial4[b][c4].
// Deterministic: fixed row partition, sequential accumulation per thread.
// ---------------------------------------------------------------------------
__global__ __launch_bounds__(256)
void k_colsum(const float4* __restrict__ x4, const int* __restrict__ deg,
              float4* __restrict__ partial4, int n) {
    __shared__ float4 lds[8][32];
    int t = threadIdx.x;
    int c4 = t & 31;          // float4 column group 0..31 (covers 128 cols)
    int ro = t >> 5;          // row offset 0..7
    int rows_per = (n + (int)gridDim.x - 1) / (int)gridDim.x;
    int rbeg = blockIdx.x * rows_per;
    int rend = rbeg + rows_per; if (rend > n) rend = n;
    float4 acc = make_float4(0.f, 0.f, 0.f, 0.f);
    for (int r = rbeg + ro; r < rend; r += 8) {
        float dv = 1.0f / sqrtf((float)deg[r]);   // broadcast load (same r per 32 lanes)
        float4 v = x4[(size_t)r * (F_IN / 4) + c4];
        acc.x += dv * v.x; acc.y += dv * v.y;
        acc.z += dv * v.z; acc.w += dv * v.w;
    }
    lds[ro][c4] = acc;
    __syncthreads();
    if (ro == 0) {
        float4 s = lds[0][c4];
        #pragma unroll
        for (int g = 1; g < 8; ++g) {
            float4 v = lds[g][c4];
            s.x += v.x; s.y += v.y; s.z += v.z; s.w += v.w;
        }
        partial4[(size_t)blockIdx.x * (F_IN / 4) + c4] = s;
    }
}

// ---------------------------------------------------------------------------
// Kernel C: single 1024-thread block.
// Phase 1: reduce nparts partials -> s[128] (32-way strided + LDS tree).
// Phase 2: agg[f] = sum_k s[k]*W[k,f], k split 4 ways across thread groups.
// ---------------------------------------------------------------------------
__global__ __launch_bounds__(1024)
void k_reduce_agg(const float4* __restrict__ partial4, int nparts,
                  const float* __restrict__ W, float* __restrict__ agg) {
    __shared__ float4 lds[32][32];
    __shared__ float s[F_IN];
    __shared__ float aggLds[4][F_OUT];
    int t = threadIdx.x;
    int c4 = t & 31;
    int g  = t >> 5;              // 0..31
    {
        float4 acc = make_float4(0.f, 0.f, 0.f, 0.f);
        for (int b = g; b < nparts; b += 32) {
            float4 v = partial4[(size_t)b * (F_IN / 4) + c4];
            acc.x += v.x; acc.y += v.y; acc.z += v.z; acc.w += v.w;
        }
        lds[g][c4] = acc;
    }
    __syncthreads();
    for (int st = 16; st > 0; st >>= 1) {
        if (g < st) {
            float4 o = lds[g + st][c4];
            float4 v = lds[g][c4];
            v.x += o.x; v.y += o.y; v.z += o.z; v.w += o.w;
            lds[g][c4] = v;
        }
        __syncthreads();
    }
    if (g == 0) {
        float4 v = lds[0][c4];
        s[c4 * 4 + 0] = v.x; s[c4 * 4 + 1] = v.y;
        s[c4 * 4 + 2] = v.z; s[c4 * 4 + 3] = v.w;
    }
    __syncthreads();
    {
        int f  = t & 255;         // output feature
        int kg = t >> 8;          // 0..3 : k-chunk
        float acc = 0.f;
        #pragma unroll 8
        for (int k = kg * 32; k < kg * 32 + 32; ++k)
            acc += s[k] * W[(size_t)k * F_OUT + f];  // s[k] LDS broadcast
        aggLds[kg][f] = acc;
    }
    __syncthreads();
    if (t < F_OUT)
        agg[t] = aggLds[0][t] + aggLds[1][t] + aggLds[2][t] + aggLds[3][t];
}

// ---------------------------------------------------------------------------
// Kernel D: out[n,f] = dinv[n]*agg[f] + bias[f], float4-vectorized.
// ---------------------------------------------------------------------------
__global__ void k_outer(const int* __restrict__ deg,
                        const float* __restrict__ agg,
                        const float* __restrict__ bias,
                        float4* __restrict__ out4, int n) {
    int i = blockIdx.x * blockDim.x + threadIdx.x;
    const int per_row = F_OUT / 4;       // 64
    int total = n * per_row;
    if (i >= total) return;
    int node = i >> 6;
    int f4   = i & 63;
    float d = 1.0f / sqrtf((float)deg[node]);
    float4 a  = ((const float4*)agg)[f4];
    float4 bb = ((const float4*)bias)[f4];
    float4 o;
    o.x = fmaf(d, a.x, bb.x);
    o.y = fmaf(d, a.y, bb.y);
    o.z = fmaf(d, a.z, bb.z);
    o.w = fmaf(d, a.w, bb.w);
    out4[i] = o;
}

// ---------------------------------------------------------------------------
static inline size_t align_up(size_t v, size_t a) { return (v + a - 1) & ~(a - 1); }

extern "C" void kernel_launch(void* const* d_in, const int* in_sizes, int n_in,
                              void* d_out, int out_size, void* d_ws, size_t ws_size,
                              hipStream_t stream) {
    const float* x    = (const float*)d_in[0];
    const int*   ei   = (const int*)  d_in[1];
    const float* W    = (const float*)d_in[2];
    const float* bias = (const float*)d_in[3];

    const int n = in_sizes[0] / F_IN;     // 12000
    const int E = in_sizes[1] / 2;        // 384000
    const int row_words = (n + 31) / 32;  // 375

    // workspace layout: [deg n*4][bitmap n*row_words*4][partial 512*128*4][agg 256*4]
    char* ws = (char*)d_ws;
    size_t deg_bytes = (size_t)n * 4;
    size_t bm_off    = align_up(deg_bytes, 256);
    size_t bm_bytes_full = (size_t)n * row_words * 4;
    size_t p_off     = align_up(bm_off + bm_bytes_full, 256);
    const int NB = 512;                   // colsum blocks
    size_t p_bytes   = (size_t)NB * F_IN * 4;
    size_t agg_off   = align_up(p_off + p_bytes, 256);

    int*      deg      = (int*)ws;
    unsigned* bm       = (unsigned*)(ws + bm_off);
    float4*   partial4 = (float4*)(ws + p_off);
    float*    agg      = (float*)(ws + agg_off);

    // chunk the bitmap if workspace is small (normally a single chunk)
    size_t need = agg_off + (size_t)F_OUT * 4;
    int rows_per_chunk = n;
    if (need > ws_size) {
        size_t avail = ws_size - (bm_off + p_bytes + (size_t)F_OUT * 4 + 1024);
        long long fit = (long long)(avail / ((size_t)row_words * 4));
        rows_per_chunk = fit > 0 ? (int)((fit < n) ? fit : n) : 1;
    }

    bool first = true;
    for (int r0 = 0; r0 < n; r0 += rows_per_chunk) {
        int rows = n - r0; if (rows > rows_per_chunk) rows = rows_per_chunk;
        if (first) {
            // one memset covers deg + bitmap (contiguous range)
            (void)hipMemsetAsync(ws, 0, bm_off + (size_t)rows * row_words * 4, stream);
            first = false;
        } else {
            (void)hipMemsetAsync(bm, 0, (size_t)rows * row_words * 4, stream);
        }
        k_edges<<<(E + 255) / 256, 256, 0, stream>>>(ei, E, bm, deg, r0, r0 + rows, row_words);
    }

    k_colsum<<<NB, 256, 0, stream>>>((const float4*)x, deg, partial4, n);
    k_reduce_agg<<<1, 1024, 0, stream>>>(partial4, NB, W, agg);

    int total4 = n * (F_OUT / 4);
    k_outer<<<(total4 + 255) / 256, 256, 0, stream>>>(deg, agg, bias, (float4*)d_out, n);
}

// Round 4
// 65.931 us; speedup vs baseline: 1.6200x; 1.5703x over previous
//
#include <hip/hip_runtime.h>
#include <math.h>

#define F_IN 128
#define F_OUT 256

// ---------------------------------------------------------------------------
// Kernel A: set adjacency bits (symmetric). Fire-and-forget atomicOr —
// idempotent => deterministic; no return value used => no round-trip
// dependency chain (round-3 lesson: returning atomicOr + dependent
// atomicAdd cost +30 µs).
// ---------------------------------------------------------------------------
__global__ void k_set_bits(const int* __restrict__ ei, int E,
                           unsigned* __restrict__ bm, int r0, int r1,
                           int row_words) {
    int e = blockIdx.x * blockDim.x + threadIdx.x;
    if (e >= E) return;
    int a = ei[e];
    int b = ei[E + e];
    if (a >= r0 && a < r1)
        atomicOr(&bm[(size_t)(a - r0) * row_words + (b >> 5)], 1u << (b & 31));
    if (b >= r0 && b < r1)
        atomicOr(&bm[(size_t)(b - r0) * row_words + (a >> 5)], 1u << (a & 31));
}

// ---------------------------------------------------------------------------
// Kernel B: popcount bitmap rows -> dinv = 1/sqrt(deg).
// 256-thread blocks, one 64-lane wave per row (4 rows/block).
// Coalesced word reads (row_words padded to multiple of 64).
// ---------------------------------------------------------------------------
__global__ __launch_bounds__(256)
void k_degree(const unsigned* __restrict__ bm, float* __restrict__ dinv,
              int r0, int rows, int row_words) {
    int wave = threadIdx.x >> 6;
    int lane = threadIdx.x & 63;
    int row  = blockIdx.x * 4 + wave;
    if (row >= rows) return;
    const unsigned* p = bm + (size_t)row * row_words;
    int cnt = 0;
    for (int w = lane; w < row_words; w += 64)   // 6 iters at row_words=384
        cnt += __popc(p[w]);
    #pragma unroll
    for (int off = 32; off > 0; off >>= 1)
        cnt += __shfl_down(cnt, off, 64);
    if (lane == 0)
        dinv[r0 + row] = 1.0f / sqrtf((float)cnt);  // deg==0 -> inf, matches ref
}

// ---------------------------------------------------------------------------
// Kernel C: partial weighted column sums of x, float4-vectorized.
// 512 blocks x 256 threads; thread (ro,c4) strides rows by 8.
// Deterministic: fixed partition, sequential per-thread accumulation.
// ---------------------------------------------------------------------------
__global__ __launch_bounds__(256)
void k_colsum(const float4* __restrict__ x4, const float* __restrict__ dinv,
              float4* __restrict__ partial4, int n) {
    __shared__ float4 lds[8][32];
    int t = threadIdx.x;
    int c4 = t & 31;          // float4 column group (covers 128 cols)
    int ro = t >> 5;          // 0..7
    int rows_per = (n + (int)gridDim.x - 1) / (int)gridDim.x;
    int rbeg = blockIdx.x * rows_per;
    int rend = rbeg + rows_per; if (rend > n) rend = n;
    float4 acc = make_float4(0.f, 0.f, 0.f, 0.f);
    for (int r = rbeg + ro; r < rend; r += 8) {
        float dv = dinv[r];                       // broadcast per 32 lanes
        float4 v = x4[(size_t)r * (F_IN / 4) + c4];
        acc.x += dv * v.x; acc.y += dv * v.y;
        acc.z += dv * v.z; acc.w += dv * v.w;
    }
    lds[ro][c4] = acc;
    __syncthreads();
    if (ro == 0) {
        float4 s = lds[0][c4];
        #pragma unroll
        for (int g = 1; g < 8; ++g) {
            float4 v = lds[g][c4];
            s.x += v.x; s.y += v.y; s.z += v.z; s.w += v.w;
        }
        partial4[(size_t)blockIdx.x * (F_IN / 4) + c4] = s;
    }
}

// ---------------------------------------------------------------------------
// Kernel D: single 1024-thread block. Reduce partials -> s[128], then
// agg[f] = sum_k s[k]*W[k,f] with 4-way k-split.
// ---------------------------------------------------------------------------
__global__ __launch_bounds__(1024)
void k_reduce_agg(const float4* __restrict__ partial4, int nparts,
                  const float* __restrict__ W, float* __restrict__ agg) {
    __shared__ float4 lds[32][32];
    __shared__ float s[F_IN];
    __shared__ float aggLds[4][F_OUT];
    int t = threadIdx.x;
    int c4 = t & 31;
    int g  = t >> 5;              // 0..31
    {
        float4 acc = make_float4(0.f, 0.f, 0.f, 0.f);
        for (int b = g; b < nparts; b += 32) {
            float4 v = partial4[(size_t)b * (F_IN / 4) + c4];
            acc.x += v.x; acc.y += v.y; acc.z += v.z; acc.w += v.w;
        }
        lds[g][c4] = acc;
    }
    __syncthreads();
    for (int st = 16; st > 0; st >>= 1) {
        if (g < st) {
            float4 o = lds[g + st][c4];
            float4 v = lds[g][c4];
            v.x += o.x; v.y += o.y; v.z += o.z; v.w += o.w;
            lds[g][c4] = v;
        }
        __syncthreads();
    }
    if (g == 0) {
        float4 v = lds[0][c4];
        s[c4 * 4 + 0] = v.x; s[c4 * 4 + 1] = v.y;
        s[c4 * 4 + 2] = v.z; s[c4 * 4 + 3] = v.w;
    }
    __syncthreads();
    {
        int f  = t & 255;
        int kg = t >> 8;          // 0..3
        float acc = 0.f;
        #pragma unroll 8
        for (int k = kg * 32; k < kg * 32 + 32; ++k)
            acc += s[k] * W[(size_t)k * F_OUT + f];
        aggLds[kg][f] = acc;
    }
    __syncthreads();
    if (t < F_OUT)
        agg[t] = aggLds[0][t] + aggLds[1][t] + aggLds[2][t] + aggLds[3][t];
}

// ---------------------------------------------------------------------------
// Kernel E: out[n,f] = dinv[n]*agg[f] + bias[f], float4-vectorized.
// ---------------------------------------------------------------------------
__global__ void k_outer(const float* __restrict__ dinv,
                        const float* __restrict__ agg,
                        const float* __restrict__ bias,
                        float4* __restrict__ out4, int n) {
    int i = blockIdx.x * blockDim.x + threadIdx.x;
    const int per_row = F_OUT / 4;       // 64
    int total = n * per_row;
    if (i >= total) return;
    int node = i >> 6;
    int f4   = i & 63;
    float d = dinv[node];                // 64 consecutive threads share node
    float4 a  = ((const float4*)agg)[f4];
    float4 bb = ((const float4*)bias)[f4];
    float4 o;
    o.x = fmaf(d, a.x, bb.x);
    o.y = fmaf(d, a.y, bb.y);
    o.z = fmaf(d, a.z, bb.z);
    o.w = fmaf(d, a.w, bb.w);
    out4[i] = o;
}

// ---------------------------------------------------------------------------
static inline size_t align_up(size_t v, size_t a) { return (v + a - 1) & ~(a - 1); }

extern "C" void kernel_launch(void* const* d_in, const int* in_sizes, int n_in,
                              void* d_out, int out_size, void* d_ws, size_t ws_size,
                              hipStream_t stream) {
    const float* x    = (const float*)d_in[0];
    const int*   ei   = (const int*)  d_in[1];
    const float* W    = (const float*)d_in[2];
    const float* bias = (const float*)d_in[3];

    const int n = in_sizes[0] / F_IN;     // 12000
    const int E = in_sizes[1] / 2;        // 384000
    // words per bitmap row, padded to a multiple of 64 so a wave reads whole
    // rows coalesced with no tail masking (pad bits never set: ids < n).
    const int row_words = (int)align_up((size_t)((n + 31) / 32), 64); // 384

    // workspace layout: [dinv n*4][partial NB*F_IN*4][agg F_OUT*4][bitmap ...]
    char* ws = (char*)d_ws;
    const int NB = 512;
    size_t off = 0;
    float*  dinv     = (float*)(ws + off); off = align_up(off + (size_t)n * 4, 256);
    float4* partial4 = (float4*)(ws + off); off = align_up(off + (size_t)NB * F_IN * 4, 256);
    float*  agg      = (float*)(ws + off); off = align_up(off + (size_t)F_OUT * 4, 256);
    unsigned* bm     = (unsigned*)(ws + off);

    // chunk the bitmap if workspace is small (normally a single chunk)
    size_t avail = (ws_size > off) ? (ws_size - off) : 0;
    long long fit = (long long)(avail / ((size_t)row_words * 4));
    int rows_per_chunk = (fit >= n) ? n : (fit > 0 ? (int)fit : 1);

    for (int r0 = 0; r0 < n; r0 += rows_per_chunk) {
        int rows = n - r0; if (rows > rows_per_chunk) rows = rows_per_chunk;
        (void)hipMemsetAsync(bm, 0, (size_t)rows * row_words * 4, stream);
        k_set_bits<<<(E + 255) / 256, 256, 0, stream>>>(ei, E, bm, r0, r0 + rows, row_words);
        k_degree<<<(rows + 3) / 4, 256, 0, stream>>>(bm, dinv, r0, rows, row_words);
    }

    k_colsum<<<NB, 256, 0, stream>>>((const float4*)x, dinv, partial4, n);
    k_reduce_agg<<<1, 1024, 0, stream>>>(partial4, NB, W, agg);

    int total4 = n * (F_OUT / 4);
    k_outer<<<(total4 + 255) / 256, 256, 0, stream>>>(dinv, agg, bias, (float4*)d_out, n);
}

// Round 5
// 65.766 us; speedup vs baseline: 1.6241x; 1.0025x over previous
//
#include <hip/hip_runtime.h>
#include <math.h>

#define F_IN 128
#define F_OUT 256

// ---------------------------------------------------------------------------
// Kernel Z: zero the bitmap. rocclr's fillBufferAligned runs at 434 GB/s
// (tiny grid, 8% occupancy) -> 42 us for 18.4 MB. A grid-stride float4
// zero kernel hits ~6 TB/s -> ~3.3 us.
// ---------------------------------------------------------------------------
__global__ __launch_bounds__(256)
void k_zero(float4* __restrict__ p, size_t n4) {
    size_t i = (size_t)blockIdx.x * blockDim.x + threadIdx.x;
    size_t stride = (size_t)gridDim.x * blockDim.x;
    float4 z = make_float4(0.f, 0.f, 0.f, 0.f);
    for (; i < n4; i += stride) p[i] = z;
}

// ---------------------------------------------------------------------------
// Kernel A: set adjacency bits (symmetric). Fire-and-forget atomicOr —
// idempotent => deterministic; no return value used => no round-trip
// dependency chain (round-3 lesson: returning atomicOr + dependent
// atomicAdd cost +30 µs).
// ---------------------------------------------------------------------------
__global__ void k_set_bits(const int* __restrict__ ei, int E,
                           unsigned* __restrict__ bm, int r0, int r1,
                           int row_words) {
    int e = blockIdx.x * blockDim.x + threadIdx.x;
    if (e >= E) return;
    int a = ei[e];
    int b = ei[E + e];
    if (a >= r0 && a < r1)
        atomicOr(&bm[(size_t)(a - r0) * row_words + (b >> 5)], 1u << (b & 31));
    if (b >= r0 && b < r1)
        atomicOr(&bm[(size_t)(b - r0) * row_words + (a >> 5)], 1u << (a & 31));
}

// ---------------------------------------------------------------------------
// Kernel B: popcount bitmap rows -> dinv = 1/sqrt(deg).
// 256-thread blocks, one 64-lane wave per row (4 rows/block).
// ---------------------------------------------------------------------------
__global__ __launch_bounds__(256)
void k_degree(const unsigned* __restrict__ bm, float* __restrict__ dinv,
              int r0, int rows, int row_words) {
    int wave = threadIdx.x >> 6;
    int lane = threadIdx.x & 63;
    int row  = blockIdx.x * 4 + wave;
    if (row >= rows) return;
    const unsigned* p = bm + (size_t)row * row_words;
    int cnt = 0;
    for (int w = lane; w < row_words; w += 64)   // 6 iters at row_words=384
        cnt += __popc(p[w]);
    #pragma unroll
    for (int off = 32; off > 0; off >>= 1)
        cnt += __shfl_down(cnt, off, 64);
    if (lane == 0)
        dinv[r0 + row] = 1.0f / sqrtf((float)cnt);  // deg==0 -> inf, matches ref
}

// ---------------------------------------------------------------------------
// Kernel C: partial weighted column sums of x, float4-vectorized.
// 512 blocks x 256 threads; thread (ro,c4) strides rows by 8.
// Deterministic: fixed partition, sequential per-thread accumulation.
// ---------------------------------------------------------------------------
__global__ __launch_bounds__(256)
void k_colsum(const float4* __restrict__ x4, const float* __restrict__ dinv,
              float4* __restrict__ partial4, int n) {
    __shared__ float4 lds[8][32];
    int t = threadIdx.x;
    int c4 = t & 31;          // float4 column group (covers 128 cols)
    int ro = t >> 5;          // 0..7
    int rows_per = (n + (int)gridDim.x - 1) / (int)gridDim.x;
    int rbeg = blockIdx.x * rows_per;
    int rend = rbeg + rows_per; if (rend > n) rend = n;
    float4 acc = make_float4(0.f, 0.f, 0.f, 0.f);
    for (int r = rbeg + ro; r < rend; r += 8) {
        float dv = dinv[r];                       // broadcast per 32 lanes
        float4 v = x4[(size_t)r * (F_IN / 4) + c4];
        acc.x += dv * v.x; acc.y += dv * v.y;
        acc.z += dv * v.z; acc.w += dv * v.w;
    }
    lds[ro][c4] = acc;
    __syncthreads();
    if (ro == 0) {
        float4 s = lds[0][c4];
        #pragma unroll
        for (int g = 1; g < 8; ++g) {
            float4 v = lds[g][c4];
            s.x += v.x; s.y += v.y; s.z += v.z; s.w += v.w;
        }
        partial4[(size_t)blockIdx.x * (F_IN / 4) + c4] = s;
    }
}

// ---------------------------------------------------------------------------
// Kernel D: single 1024-thread block. Reduce partials -> s[128], then
// agg[f] = sum_k s[k]*W[k,f] with 4-way k-split.
// ---------------------------------------------------------------------------
__global__ __launch_bounds__(1024)
void k_reduce_agg(const float4* __restrict__ partial4, int nparts,
                  const float* __restrict__ W, float* __restrict__ agg) {
    __shared__ float4 lds[32][32];
    __shared__ float s[F_IN];
    __shared__ float aggLds[4][F_OUT];
    int t = threadIdx.x;
    int c4 = t & 31;
    int g  = t >> 5;              // 0..31
    {
        float4 acc = make_float4(0.f, 0.f, 0.f, 0.f);
        for (int b = g; b < nparts; b += 32) {
            float4 v = partial4[(size_t)b * (F_IN / 4) + c4];
            acc.x += v.x; acc.y += v.y; acc.z += v.z; acc.w += v.w;
        }
        lds[g][c4] = acc;
    }
    __syncthreads();
    for (int st = 16; st > 0; st >>= 1) {
        if (g < st) {
            float4 o = lds[g + st][c4];
            float4 v = lds[g][c4];
            v.x += o.x; v.y += o.y; v.z += o.z; v.w += o.w;
            lds[g][c4] = v;
        }
        __syncthreads();
    }
    if (g == 0) {
        float4 v = lds[0][c4];
        s[c4 * 4 + 0] = v.x; s[c4 * 4 + 1] = v.y;
        s[c4 * 4 + 2] = v.z; s[c4 * 4 + 3] = v.w;
    }
    __syncthreads();
    {
        int f  = t & 255;
        int kg = t >> 8;          // 0..3
        float acc = 0.f;
        #pragma unroll 8
        for (int k = kg * 32; k < kg * 32 + 32; ++k)
            acc += s[k] * W[(size_t)k * F_OUT + f];
        aggLds[kg][f] = acc;
    }
    __syncthreads();
    if (t < F_OUT)
        agg[t] = aggLds[0][t] + aggLds[1][t] + aggLds[2][t] + aggLds[3][t];
}

// ---------------------------------------------------------------------------
// Kernel E: out[n,f] = dinv[n]*agg[f] + bias[f], float4-vectorized.
// ---------------------------------------------------------------------------
__global__ void k_outer(const float* __restrict__ dinv,
                        const float* __restrict__ agg,
                        const float* __restrict__ bias,
                        float4* __restrict__ out4, int n) {
    int i = blockIdx.x * blockDim.x + threadIdx.x;
    const int per_row = F_OUT / 4;       // 64
    int total = n * per_row;
    if (i >= total) return;
    int node = i >> 6;
    int f4   = i & 63;
    float d = dinv[node];                // 64 consecutive threads share node
    float4 a  = ((const float4*)agg)[f4];
    float4 bb = ((const float4*)bias)[f4];
    float4 o;
    o.x = fmaf(d, a.x, bb.x);
    o.y = fmaf(d, a.y, bb.y);
    o.z = fmaf(d, a.z, bb.z);
    o.w = fmaf(d, a.w, bb.w);
    out4[i] = o;
}

// ---------------------------------------------------------------------------
static inline size_t align_up(size_t v, size_t a) { return (v + a - 1) & ~(a - 1); }

extern "C" void kernel_launch(void* const* d_in, const int* in_sizes, int n_in,
                              void* d_out, int out_size, void* d_ws, size_t ws_size,
                              hipStream_t stream) {
    const float* x    = (const float*)d_in[0];
    const int*   ei   = (const int*)  d_in[1];
    const float* W    = (const float*)d_in[2];
    const float* bias = (const float*)d_in[3];

    const int n = in_sizes[0] / F_IN;     // 12000
    const int E = in_sizes[1] / 2;        // 384000
    // words per bitmap row, padded to a multiple of 64 so a wave reads whole
    // rows coalesced with no tail masking (pad bits never set: ids < n).
    const int row_words = (int)align_up((size_t)((n + 31) / 32), 64); // 384

    // workspace layout: [dinv n*4][partial NB*F_IN*4][agg F_OUT*4][bitmap ...]
    char* ws = (char*)d_ws;
    const int NB = 512;
    size_t off = 0;
    float*  dinv     = (float*)(ws + off); off = align_up(off + (size_t)n * 4, 256);
    float4* partial4 = (float4*)(ws + off); off = align_up(off + (size_t)NB * F_IN * 4, 256);
    float*  agg      = (float*)(ws + off); off = align_up(off + (size_t)F_OUT * 4, 256);
    unsigned* bm     = (unsigned*)(ws + off);

    // chunk the bitmap if workspace is small (normally a single chunk)
    size_t avail = (ws_size > off) ? (ws_size - off) : 0;
    long long fit = (long long)(avail / ((size_t)row_words * 4));
    int rows_per_chunk = (fit >= n) ? n : (fit > 0 ? (int)fit : 1);

    for (int r0 = 0; r0 < n; r0 += rows_per_chunk) {
        int rows = n - r0; if (rows > rows_per_chunk) rows = rows_per_chunk;
        size_t bm_bytes = (size_t)rows * row_words * 4;   // multiple of 16
        size_t n4 = bm_bytes / 16;
        int zgrid = (int)((n4 + 255) / 256);
        if (zgrid > 2048) zgrid = 2048;
        k_zero<<<zgrid, 256, 0, stream>>>((float4*)bm, n4);
        k_set_bits<<<(E + 255) / 256, 256, 0, stream>>>(ei, E, bm, r0, r0 + rows, row_words);
        k_degree<<<(rows + 3) / 4, 256, 0, stream>>>(bm, dinv, r0, rows, row_words);
    }

    k_colsum<<<NB, 256, 0, stream>>>((const float4*)x, dinv, partial4, n);
    k_reduce_agg<<<1, 1024, 0, stream>>>(partial4, NB, W, agg);

    int total4 = n * (F_OUT / 4);
    k_outer<<<(total4 + 255) / 256, 256, 0, stream>>>(dinv, agg, bias, (float4*)d_out, n);
}

// Round 6
// 64.009 us; speedup vs baseline: 1.6687x; 1.0274x over previous
//
#include <hip/hip_runtime.h>
#include <math.h>

#define F_IN 128
#define F_OUT 256
#define NGRP 8   // MI355X XCD count; blockIdx.x % 8 empirically round-robins XCDs

// ---------------------------------------------------------------------------
// XCD-affine trio: rows are split into NGRP groups of rpg rows. All three
// kernels map blockIdx&7 -> group, so each XCD's L2 owns one 2.3 MB bitmap
// slice across zero -> atomicOr -> popcount. Correctness does not depend on
// the block->XCD mapping (only locality does).
// ---------------------------------------------------------------------------

// Kernel Z: zero the bitmap slice-by-slice (float4 streaming stores).
__global__ __launch_bounds__(256)
void k_zero_xcd(float4* __restrict__ bm4, int rpg, int n, int rw4) {
    int g    = blockIdx.x & (NGRP - 1);
    int blk  = blockIdx.x >> 3;
    int nblk = gridDim.x >> 3;
    int r0 = g * rpg;
    int r1 = r0 + rpg; if (r1 > n) r1 = n;
    if (r0 >= r1) return;
    size_t w0 = (size_t)r0 * rw4, w1 = (size_t)r1 * rw4;
    float4 z = make_float4(0.f, 0.f, 0.f, 0.f);
    for (size_t i = w0 + (size_t)blk * blockDim.x + threadIdx.x; i < w1;
         i += (size_t)nblk * blockDim.x)
        bm4[i] = z;
}

// Kernel A: set adjacency bits (symmetric), group-filtered fire-and-forget
// atomicOr (idempotent => deterministic). Each group scans the full edge
// list (3 MB, L3-resident) and touches only its own L2-resident slice.
__global__ __launch_bounds__(256)
void k_set_bits_xcd(const int* __restrict__ ei, int E,
                    unsigned* __restrict__ bm, int rpg, int n, int row_words) {
    int g    = blockIdx.x & (NGRP - 1);
    int blk  = blockIdx.x >> 3;
    int nblk = gridDim.x >> 3;
    int r0 = g * rpg;
    int r1 = r0 + rpg; if (r1 > n) r1 = n;
    for (int e = blk * (int)blockDim.x + (int)threadIdx.x; e < E;
         e += nblk * (int)blockDim.x) {
        int a = ei[e];
        int b = ei[E + e];
        if (a >= r0 && a < r1)
            atomicOr(&bm[(size_t)a * row_words + (b >> 5)], 1u << (b & 31));
        if (b >= r0 && b < r1)
            atomicOr(&bm[(size_t)b * row_words + (a >> 5)], 1u << (a & 31));
    }
}

// Kernel B: popcount rows -> dinv = 1/sqrt(deg). One wave per row,
// 4 rows per block, same group mapping (reads hit the local L2 slice).
__global__ __launch_bounds__(256)
void k_degree_xcd(const unsigned* __restrict__ bm, float* __restrict__ dinv,
                  int rpg, int n, int row_words) {
    int g    = blockIdx.x & (NGRP - 1);
    int blk  = blockIdx.x >> 3;
    int wave = threadIdx.x >> 6;
    int lane = threadIdx.x & 63;
    int r0 = g * rpg;
    int r1 = r0 + rpg; if (r1 > n) r1 = n;
    int row = r0 + blk * 4 + wave;
    if (row >= r1) return;
    const unsigned* p = bm + (size_t)row * row_words;
    int cnt = 0;
    for (int w = lane; w < row_words; w += 64)   // 6 iters at row_words=384
        cnt += __popc(p[w]);
    #pragma unroll
    for (int off = 32; off > 0; off >>= 1)
        cnt += __shfl_down(cnt, off, 64);
    if (lane == 0)
        dinv[row] = 1.0f / sqrtf((float)cnt);    // deg==0 -> inf, matches ref
}

// ---------------------------------------------------------------------------
// Fallback (tiny workspace only): chunked simple versions.
// ---------------------------------------------------------------------------
__global__ void k_set_bits_simple(const int* __restrict__ ei, int E,
                                  unsigned* __restrict__ bm, int r0, int r1,
                                  int row_words) {
    int e = blockIdx.x * blockDim.x + threadIdx.x;
    if (e >= E) return;
    int a = ei[e];
    int b = ei[E + e];
    if (a >= r0 && a < r1)
        atomicOr(&bm[(size_t)(a - r0) * row_words + (b >> 5)], 1u << (b & 31));
    if (b >= r0 && b < r1)
        atomicOr(&bm[(size_t)(b - r0) * row_words + (a >> 5)], 1u << (a & 31));
}

__global__ __launch_bounds__(256)
void k_degree_simple(const unsigned* __restrict__ bm, float* __restrict__ dinv,
                     int r0, int rows, int row_words) {
    int wave = threadIdx.x >> 6;
    int lane = threadIdx.x & 63;
    int row  = blockIdx.x * 4 + wave;
    if (row >= rows) return;
    const unsigned* p = bm + (size_t)row * row_words;
    int cnt = 0;
    for (int w = lane; w < row_words; w += 64)
        cnt += __popc(p[w]);
    #pragma unroll
    for (int off = 32; off > 0; off >>= 1)
        cnt += __shfl_down(cnt, off, 64);
    if (lane == 0)
        dinv[r0 + row] = 1.0f / sqrtf((float)cnt);
}

__global__ __launch_bounds__(256)
void k_zero_simple(float4* __restrict__ p, size_t n4) {
    size_t i = (size_t)blockIdx.x * blockDim.x + threadIdx.x;
    size_t stride = (size_t)gridDim.x * blockDim.x;
    float4 z = make_float4(0.f, 0.f, 0.f, 0.f);
    for (; i < n4; i += stride) p[i] = z;
}

// ---------------------------------------------------------------------------
// Kernel C: partial weighted column sums of x, float4-vectorized.
// ---------------------------------------------------------------------------
__global__ __launch_bounds__(256)
void k_colsum(const float4* __restrict__ x4, const float* __restrict__ dinv,
              float4* __restrict__ partial4, int n) {
    __shared__ float4 lds[8][32];
    int t = threadIdx.x;
    int c4 = t & 31;
    int ro = t >> 5;
    int rows_per = (n + (int)gridDim.x - 1) / (int)gridDim.x;
    int rbeg = blockIdx.x * rows_per;
    int rend = rbeg + rows_per; if (rend > n) rend = n;
    float4 acc = make_float4(0.f, 0.f, 0.f, 0.f);
    for (int r = rbeg + ro; r < rend; r += 8) {
        float dv = dinv[r];
        float4 v = x4[(size_t)r * (F_IN / 4) + c4];
        acc.x += dv * v.x; acc.y += dv * v.y;
        acc.z += dv * v.z; acc.w += dv * v.w;
    }
    lds[ro][c4] = acc;
    __syncthreads();
    if (ro == 0) {
        float4 s = lds[0][c4];
        #pragma unroll
        for (int g = 1; g < 8; ++g) {
            float4 v = lds[g][c4];
            s.x += v.x; s.y += v.y; s.z += v.z; s.w += v.w;
        }
        partial4[(size_t)blockIdx.x * (F_IN / 4) + c4] = s;
    }
}

// ---------------------------------------------------------------------------
// Kernel D: single 1024-thread block. Reduce partials -> s[128], then
// agg[f] = sum_k s[k]*W[k,f] with 4-way k-split.
// ---------------------------------------------------------------------------
__global__ __launch_bounds__(1024)
void k_reduce_agg(const float4* __restrict__ partial4, int nparts,
                  const float* __restrict__ W, float* __restrict__ agg) {
    __shared__ float4 lds[32][32];
    __shared__ float s[F_IN];
    __shared__ float aggLds[4][F_OUT];
    int t = threadIdx.x;
    int c4 = t & 31;
    int g  = t >> 5;
    {
        float4 acc = make_float4(0.f, 0.f, 0.f, 0.f);
        for (int b = g; b < nparts; b += 32) {
            float4 v = partial4[(size_t)b * (F_IN / 4) + c4];
            acc.x += v.x; acc.y += v.y; acc.z += v.z; acc.w += v.w;
        }
        lds[g][c4] = acc;
    }
    __syncthreads();
    for (int st = 16; st > 0; st >>= 1) {
        if (g < st) {
            float4 o = lds[g + st][c4];
            float4 v = lds[g][c4];
            v.x += o.x; v.y += o.y; v.z += o.z; v.w += o.w;
            lds[g][c4] = v;
        }
        __syncthreads();
    }
    if (g == 0) {
        float4 v = lds[0][c4];
        s[c4 * 4 + 0] = v.x; s[c4 * 4 + 1] = v.y;
        s[c4 * 4 + 2] = v.z; s[c4 * 4 + 3] = v.w;
    }
    __syncthreads();
    {
        int f  = t & 255;
        int kg = t >> 8;
        float acc = 0.f;
        #pragma unroll 8
        for (int k = kg * 32; k < kg * 32 + 32; ++k)
            acc += s[k] * W[(size_t)k * F_OUT + f];
        aggLds[kg][f] = acc;
    }
    __syncthreads();
    if (t < F_OUT)
        agg[t] = aggLds[0][t] + aggLds[1][t] + aggLds[2][t] + aggLds[3][t];
}

// ---------------------------------------------------------------------------
// Kernel E: out[n,f] = dinv[n]*agg[f] + bias[f], float4-vectorized.
// ---------------------------------------------------------------------------
__global__ void k_outer(const float* __restrict__ dinv,
                        const float* __restrict__ agg,
                        const float* __restrict__ bias,
                        float4* __restrict__ out4, int n) {
    int i = blockIdx.x * blockDim.x + threadIdx.x;
    const int per_row = F_OUT / 4;
    int total = n * per_row;
    if (i >= total) return;
    int node = i >> 6;
    int f4   = i & 63;
    float d = dinv[node];
    float4 a  = ((const float4*)agg)[f4];
    float4 bb = ((const float4*)bias)[f4];
    float4 o;
    o.x = fmaf(d, a.x, bb.x);
    o.y = fmaf(d, a.y, bb.y);
    o.z = fmaf(d, a.z, bb.z);
    o.w = fmaf(d, a.w, bb.w);
    out4[i] = o;
}

// ---------------------------------------------------------------------------
static inline size_t align_up(size_t v, size_t a) { return (v + a - 1) & ~(a - 1); }

extern "C" void kernel_launch(void* const* d_in, const int* in_sizes, int n_in,
                              void* d_out, int out_size, void* d_ws, size_t ws_size,
                              hipStream_t stream) {
    const float* x    = (const float*)d_in[0];
    const int*   ei   = (const int*)  d_in[1];
    const float* W    = (const float*)d_in[2];
    const float* bias = (const float*)d_in[3];

    const int n = in_sizes[0] / F_IN;     // 12000
    const int E = in_sizes[1] / 2;        // 384000
    // words per bitmap row, padded to a multiple of 64 so a wave reads whole
    // rows coalesced with no tail masking (pad bits never set: ids < n).
    const int row_words = (int)align_up((size_t)((n + 31) / 32), 64); // 384
    const int rw4 = row_words / 4;                                    // 96

    // workspace layout: [dinv n*4][partial NB*F_IN*4][agg F_OUT*4][bitmap ...]
    char* ws = (char*)d_ws;
    const int NB = 512;
    size_t off = 0;
    float*  dinv     = (float*)(ws + off); off = align_up(off + (size_t)n * 4, 256);
    float4* partial4 = (float4*)(ws + off); off = align_up(off + (size_t)NB * F_IN * 4, 256);
    float*  agg      = (float*)(ws + off); off = align_up(off + (size_t)F_OUT * 4, 256);
    unsigned* bm     = (unsigned*)(ws + off);

    size_t bm_bytes_full = (size_t)n * row_words * 4;   // 18.4 MB
    size_t avail = (ws_size > off) ? (ws_size - off) : 0;

    if (avail >= bm_bytes_full) {
        // Fast path: XCD-affine zero -> set-bits -> popcount.
        const int rpg = (n + NGRP - 1) / NGRP;          // 1500
        k_zero_xcd<<<NGRP * 128, 256, 0, stream>>>((float4*)bm, rpg, n, rw4);
        k_set_bits_xcd<<<NGRP * 128, 256, 0, stream>>>(ei, E, bm, rpg, n, row_words);
        int blk_per_grp = (rpg + 3) / 4;                // 375
        k_degree_xcd<<<NGRP * blk_per_grp, 256, 0, stream>>>(bm, dinv, rpg, n, row_words);
    } else {
        // Fallback: chunked simple path (tiny workspace only).
        long long fit = (long long)(avail / ((size_t)row_words * 4));
        int rows_per_chunk = fit > 0 ? (int)((fit < n) ? fit : n) : 1;
        for (int r0 = 0; r0 < n; r0 += rows_per_chunk) {
            int rows = n - r0; if (rows > rows_per_chunk) rows = rows_per_chunk;
            size_t n4 = (size_t)rows * row_words / 4;
            int zgrid = (int)((n4 + 255) / 256); if (zgrid > 2048) zgrid = 2048;
            k_zero_simple<<<zgrid, 256, 0, stream>>>((float4*)bm, n4);
            k_set_bits_simple<<<(E + 255) / 256, 256, 0, stream>>>(ei, E, bm, r0, r0 + rows, row_words);
            k_degree_simple<<<(rows + 3) / 4, 256, 0, stream>>>(bm, dinv, r0, rows, row_words);
        }
    }

    k_colsum<<<NB, 256, 0, stream>>>((const float4*)x, dinv, partial4, n);
    k_reduce_agg<<<1, 1024, 0, stream>>>(partial4, NB, W, agg);

    int total4 = n * (F_OUT / 4);
    k_outer<<<(total4 + 255) / 256, 256, 0, stream>>>(dinv, agg, bias, (float4*)d_out, n);
}